// Round 9
// baseline (212.242 us; speedup 1.0000x reference)
//
#include <hip/hip_runtime.h>
#include <math.h>

#define N_NODE    1000000
#define N_BOND    100000
#define K_TWIST   40
#define MAX_ORDER 8
#define N_DOMAIN  10000
#define N_PER_DOM 100           // N_NODE / N_DOMAIN
#define N_GROUP   12500         // N_BOND / MAX_ORDER
#define N_TWIST   500000        // N_GROUP * K_TWIST  (nodes >= N_TWIST never twisted)
#define SIGMA_MAXF 3.14159265358979323846f

// Layout:
//   out-high floats [1.5M, 2.7M): M_lv = 8 levels x 12500 x 12 floats.
//     Written via device-scope atomics in mega_k; read plain by apply_low
//     after the dispatch boundary (R8-proven). apply_high overwrites last.
//   ws: rt 480,000 B + flags 50,000 B = 530,000 B (R8-proven footprint).
// Cost model (R4..R8): ~78 us fixed harness overhead + ~10 us per dependent
// dispatch boundary -> 3 dispatches total.
// R6 lesson: 1 workgroup = no MLP. R4 lesson: grid.sync = 110 us each.
// R8 lesson: atomic dataflow protocol is CORRECT on gfx950; its cost scales
// with atomic count -> this round cuts bp traffic + 2 dispatches.
// Flags are POISON-TOLERANT: valid values 1..8; 0xAAAAAAAA (ws poison) reads
// as "unwritten" (>= 0x10000000) -> no zeroing pass needed.

#define MLV_OFF    1500000
#define MLV_STRIDE 150000
#define SPIN_MAX   1000000

__device__ inline unsigned long long pack2f(float a, float b)
{
    return ((unsigned long long)__float_as_uint(b) << 32) | __float_as_uint(a);
}

__device__ inline void unpack2f(unsigned long long w, float* a, float* b)
{
    *a = __uint_as_float((unsigned int)(w & 0xffffffffull));
    *b = __uint_as_float((unsigned int)(w >> 32));
}

// valid flag values are 1..8; poison (0xAA..) and garbage read as >= 2^28.
__device__ inline void spin_flag(unsigned int* f, unsigned int need)
{
    for (int it = 0; it < SPIN_MAX; ++it) {
        unsigned int v = atomicAdd(f, 0u);
        if (v < 0x10000000u && v >= need) return;
    }
}

__device__ inline void read_M(unsigned long long* mp, float m[12])
{
    unsigned long long w0 = atomicAdd(&mp[0], 0ull);
    unsigned long long w1 = atomicAdd(&mp[1], 0ull);
    unsigned long long w2 = atomicAdd(&mp[2], 0ull);
    unsigned long long w3 = atomicAdd(&mp[3], 0ull);
    unsigned long long w4 = atomicAdd(&mp[4], 0ull);
    unsigned long long w5 = atomicAdd(&mp[5], 0ull);
    unpack2f(w0, &m[0], &m[1]);  unpack2f(w1, &m[2], &m[3]);
    unpack2f(w2, &m[4], &m[5]);  unpack2f(w3, &m[6], &m[7]);
    unpack2f(w4, &m[8], &m[9]);  unpack2f(w5, &m[10], &m[11]);
}

// ---------------------------------------------------------------------------
// Kabsch 3x3 SVD from 15 sums (double Jacobi on H^T H) — numerics identical
// to the R1..R8-verified version.
// ---------------------------------------------------------------------------
__device__ inline void cross3d(const double a[3], const double b[3], double r[3])
{
    r[0] = a[1]*b[2] - a[2]*b[1];
    r[1] = a[2]*b[0] - a[0]*b[2];
    r[2] = a[0]*b[1] - a[1]*b[0];
}

__device__ void kabsch_from_sums(const float* s, float* __restrict__ rt)
{
    const double inv_n = 1.0 / (double)N_PER_DOM;
    double sP[3] = { s[0], s[1], s[2] };
    double sQ[3] = { s[3], s[4], s[5] };
    double H[3][3];
    #pragma unroll
    for (int i = 0; i < 3; i++)
        #pragma unroll
        for (int j = 0; j < 3; j++)
            H[i][j] = (double)s[6 + 3*i + j] - sP[i]*sQ[j]*inv_n;
    double A[3][3];
    #pragma unroll
    for (int i = 0; i < 3; i++)
        #pragma unroll
        for (int j = 0; j < 3; j++)
            A[i][j] = H[0][i]*H[0][j] + H[1][i]*H[1][j] + H[2][i]*H[2][j];
    double V[3][3] = {{1,0,0},{0,1,0},{0,0,1}};
    for (int sweep = 0; sweep < 30; sweep++) {
        double off = A[0][1]*A[0][1] + A[0][2]*A[0][2] + A[1][2]*A[1][2];
        double n2  = A[0][0]*A[0][0] + A[1][1]*A[1][1] + A[2][2]*A[2][2];
        if (off <= 1e-28 * n2) break;
        for (int pp = 0; pp < 3; pp++) {
            int p = (pp == 2) ? 1 : 0;
            int q = (pp == 0) ? 1 : 2;
            double apq = A[p][q];
            if (apq == 0.0) continue;
            double tau = (A[q][q] - A[p][p]) / (2.0 * apq);
            double tj  = (tau >= 0.0 ? 1.0 : -1.0) / (fabs(tau) + sqrt(1.0 + tau*tau));
            double cj  = 1.0 / sqrt(1.0 + tj*tj);
            double sj  = tj * cj;
            int r = 3 - p - q;
            double app = A[p][p], aqq = A[q][q];
            A[p][p] = app - tj*apq;
            A[q][q] = aqq + tj*apq;
            A[p][q] = 0.0; A[q][p] = 0.0;
            double arp = A[r][p], arq = A[r][q];
            A[r][p] = cj*arp - sj*arq; A[p][r] = A[r][p];
            A[r][q] = sj*arp + cj*arq; A[q][r] = A[r][q];
            #pragma unroll
            for (int k = 0; k < 3; k++) {
                double vp = V[k][p], vq = V[k][q];
                V[k][p] = cj*vp - sj*vq;
                V[k][q] = sj*vp + cj*vq;
            }
        }
    }
    double wv[3] = { A[0][0], A[1][1], A[2][2] };
    int i0 = 0, i1 = 1, i2 = 2;
    if (wv[i0] < wv[i1]) { int t = i0; i0 = i1; i1 = t; }
    if (wv[i0] < wv[i2]) { int t = i0; i0 = i2; i2 = t; }
    if (wv[i1] < wv[i2]) { int t = i1; i1 = i2; i2 = t; }
    double v0[3] = { V[0][i0], V[1][i0], V[2][i0] };
    double v1[3] = { V[0][i1], V[1][i1], V[2][i1] };
    double v2[3] = { V[0][i2], V[1][i2], V[2][i2] };
    double s0 = sqrt(fmax(wv[i0], 0.0));
    double Rg[3][3];
    if (s0 < 1e-200) {
        Rg[0][0]=1; Rg[0][1]=0; Rg[0][2]=0;
        Rg[1][0]=0; Rg[1][1]=1; Rg[1][2]=0;
        Rg[2][0]=0; Rg[2][1]=0; Rg[2][2]=1;
    } else {
        double u0[3], u1[3], u2[3];
        #pragma unroll
        for (int i = 0; i < 3; i++)
            u0[i] = H[i][0]*v0[0] + H[i][1]*v0[1] + H[i][2]*v0[2];
        double n0 = sqrt(u0[0]*u0[0] + u0[1]*u0[1] + u0[2]*u0[2]);
        if (n0 > 0.0) { u0[0]/=n0; u0[1]/=n0; u0[2]/=n0; }
        else { u0[0]=1; u0[1]=0; u0[2]=0; }
        #pragma unroll
        for (int i = 0; i < 3; i++)
            u1[i] = H[i][0]*v1[0] + H[i][1]*v1[1] + H[i][2]*v1[2];
        double dp = u0[0]*u1[0] + u0[1]*u1[1] + u0[2]*u1[2];
        u1[0] -= dp*u0[0]; u1[1] -= dp*u0[1]; u1[2] -= dp*u0[2];
        double n1 = sqrt(u1[0]*u1[0] + u1[1]*u1[1] + u1[2]*u1[2]);
        if (n1 > 1e-12 * n0) { u1[0]/=n1; u1[1]/=n1; u1[2]/=n1; }
        else {
            double tv[3] = { (fabs(u0[0]) < 0.9) ? 1.0 : 0.0,
                             (fabs(u0[0]) < 0.9) ? 0.0 : 1.0, 0.0 };
            cross3d(u0, tv, u1);
            double nn = sqrt(u1[0]*u1[0] + u1[1]*u1[1] + u1[2]*u1[2]);
            u1[0]/=nn; u1[1]/=nn; u1[2]/=nn;
        }
        cross3d(u0, u1, u2);                    // det(U) = +1
        double c12[3]; cross3d(v1, v2, c12);
        double detV = v0[0]*c12[0] + v0[1]*c12[1] + v0[2]*c12[2];
        double dsg = (detV >= 0.0) ? 1.0 : -1.0;
        #pragma unroll
        for (int r = 0; r < 3; r++)
            #pragma unroll
            for (int c = 0; c < 3; c++)
                Rg[r][c] = v0[r]*u0[c] + v1[r]*u1[c] + dsg*v2[r]*u2[c];
    }
    double cP[3] = { sP[0]*inv_n, sP[1]*inv_n, sP[2]*inv_n };
    double cQ[3] = { sQ[0]*inv_n, sQ[1]*inv_n, sQ[2]*inv_n };
    #pragma unroll
    for (int i = 0; i < 3; i++) {
        rt[3*i+0] = (float)Rg[i][0];
        rt[3*i+1] = (float)Rg[i][1];
        rt[3*i+2] = (float)Rg[i][2];
        rt[9+i] = (float)(cQ[i] - (Rg[i][0]*cP[0] + Rg[i][1]*cP[1] + Rg[i][2]*cP[2]));
    }
}

__device__ inline void acc15(float a[15], float p0, float p1, float p2,
                             float q0, float q1, float q2)
{
    a[0]+=p0;    a[1]+=p1;    a[2]+=p2;
    a[3]+=q0;    a[4]+=q1;    a[5]+=q2;
    a[6]+=p0*q0; a[7]+=p0*q1; a[8]+=p0*q2;
    a[9]+=p1*q0; a[10]+=p1*q1;a[11]+=p1*q2;
    a[12]+=p2*q0;a[13]+=p2*q1;a[14]+=p2*q2;
}

// ---------------------------------------------------------------------------
// mega_k: ONE dispatch, 49 blocks x 256 = 12544 threads, all co-resident on
// 256 CUs (deadlock-free).
//  Stage 0: thread g pre-loads its own 8 bonds into registers (bond (g,o) is
//           read by no other thread -> no bp table, no publication).
//  Stage 1: 8 dataflow levels (R8-proven protocol): spin on endpoint groups'
//           flags >= o, RMW-read their level-(o-1) M, compose own M in regs,
//           RMW-publish M_lv[o][g], fence, flag[g] = o+1.
//  Stage 2: thread d < 10000 = domain d: high domains reduce pos directly;
//           low domains spin on their 3 covering groups' flags == 8, RMW-read
//           final Ms, reduce 100 contiguous nodes, double-Jacobi SVD -> rt.
// ---------------------------------------------------------------------------
__global__ __launch_bounds__(256) void mega_k(
    const float* __restrict__ pos, const float* __restrict__ info_level,
    const int* __restrict__ anno, const float* __restrict__ eps,
    const float* __restrict__ uni, const int* __restrict__ from_prior_p,
    float* __restrict__ out, float* __restrict__ rt,
    unsigned int* __restrict__ flags)
{
    const int g = blockIdx.x * 256 + threadIdx.x;

    // ---- Stage 0 + 1: torsion dataflow --------------------------------
    if (g < N_GROUP) {
        float bu[MAX_ORDER][3], bv[MAX_ORDER][3], bc[MAX_ORDER], bs[MAX_ORDER];
        int   bgu[MAX_ORDER], bgv[MAX_ORDER], bval[MAX_ORDER];
        const int from_prior = from_prior_p[0];
        #pragma unroll
        for (int o = 0; o < MAX_ORDER; o++) {
            int b = g * MAX_ORDER + o;
            int u = anno[3*b + 1];
            int v = anno[3*b + 2];
            float info = info_level[b];
            float ang  = eps[b] * (1.0f - info) * SIGMA_MAXF;
            if (from_prior != 0 && info == 0.0f) ang = uni[b];
            bc[o] = cosf(ang); bs[o] = sinf(ang);
            bu[o][0] = pos[3*u+0]; bu[o][1] = pos[3*u+1]; bu[o][2] = pos[3*u+2];
            bv[o][0] = pos[3*v+0]; bv[o][1] = pos[3*v+1]; bv[o][2] = pos[3*v+2];
            bgu[o] = (u < N_TWIST) ? (u / K_TWIST) : -1;
            bgv[o] = (v < N_TWIST) ? (v / K_TWIST) : -1;
            bval[o] = (anno[3*b] == o) ? 1 : 0;
        }

        float M[12];
        #pragma unroll
        for (int o = 0; o < MAX_ORDER; o++) {
            if (bval[o]) {
                float pu0 = bu[o][0], pu1 = bu[o][1], pu2 = bu[o][2];
                float pv0 = bv[o][0], pv1 = bv[o][1], pv2 = bv[o][2];
                float c = bc[o], s = bs[o];
                if (o > 0) {
                    unsigned long long* Mprev =
                        (unsigned long long*)(out + MLV_OFF + (size_t)(o-1) * MLV_STRIDE);
                    if (bgu[o] >= 0) {
                        spin_flag(&flags[bgu[o]], (unsigned int)o);
                        float m[12];
                        read_M(Mprev + 6 * bgu[o], m);
                        float a0 = m[0]*pu0 + m[1]*pu1 + m[2]*pu2 + m[9];
                        float a1 = m[3]*pu0 + m[4]*pu1 + m[5]*pu2 + m[10];
                        float a2 = m[6]*pu0 + m[7]*pu1 + m[8]*pu2 + m[11];
                        pu0 = a0; pu1 = a1; pu2 = a2;
                    }
                    if (bgv[o] >= 0) {
                        spin_flag(&flags[bgv[o]], (unsigned int)o);
                        float m[12];
                        read_M(Mprev + 6 * bgv[o], m);
                        float a0 = m[0]*pv0 + m[1]*pv1 + m[2]*pv2 + m[9];
                        float a1 = m[3]*pv0 + m[4]*pv1 + m[5]*pv2 + m[10];
                        float a2 = m[6]*pv0 + m[7]*pv1 + m[8]*pv2 + m[11];
                        pv0 = a0; pv1 = a1; pv2 = a2;
                    }
                }
                float ax = pv0-pu0, ay = pv1-pu1, az = pv2-pu2;
                float inv = 1.0f / (sqrtf(ax*ax + ay*ay + az*az) + 1e-12f);
                ax *= inv; ay *= inv; az *= inv;
                float t = 1.0f - c;
                float R00 = c + t*ax*ax,     R01 = -s*az + t*ax*ay, R02 =  s*ay + t*ax*az;
                float R10 =  s*az + t*ay*ax, R11 = c + t*ay*ay,     R12 = -s*ax + t*ay*az;
                float R20 = -s*ay + t*az*ax, R21 =  s*ax + t*az*ay, R22 = c + t*az*az;
                if (o == 0) {
                    M[0]=R00; M[1]=R01; M[2]=R02;
                    M[3]=R10; M[4]=R11; M[5]=R12;
                    M[6]=R20; M[7]=R21; M[8]=R22;
                    M[9]  = pv0 - (R00*pv0 + R01*pv1 + R02*pv2);
                    M[10] = pv1 - (R10*pv0 + R11*pv1 + R12*pv2);
                    M[11] = pv2 - (R20*pv0 + R21*pv1 + R22*pv2);
                } else {
                    float n0 = R00*M[0] + R01*M[3] + R02*M[6];
                    float n1 = R00*M[1] + R01*M[4] + R02*M[7];
                    float n2 = R00*M[2] + R01*M[5] + R02*M[8];
                    float n3 = R10*M[0] + R11*M[3] + R12*M[6];
                    float n4 = R10*M[1] + R11*M[4] + R12*M[7];
                    float n5 = R10*M[2] + R11*M[5] + R12*M[8];
                    float n6 = R20*M[0] + R21*M[3] + R22*M[6];
                    float n7 = R20*M[1] + R21*M[4] + R22*M[7];
                    float n8 = R20*M[2] + R21*M[5] + R22*M[8];
                    float d0 = M[9]-pv0, d1 = M[10]-pv1, d2 = M[11]-pv2;
                    float n9  = R00*d0 + R01*d1 + R02*d2 + pv0;
                    float n10 = R10*d0 + R11*d1 + R12*d2 + pv1;
                    float n11 = R20*d0 + R21*d1 + R22*d2 + pv2;
                    M[0]=n0; M[1]=n1; M[2]=n2; M[3]=n3; M[4]=n4; M[5]=n5;
                    M[6]=n6; M[7]=n7; M[8]=n8; M[9]=n9; M[10]=n10; M[11]=n11;
                }
            } else if (o == 0) {
                M[0]=1.f; M[1]=0.f; M[2]=0.f; M[3]=0.f; M[4]=1.f; M[5]=0.f;
                M[6]=0.f; M[7]=0.f; M[8]=1.f; M[9]=0.f; M[10]=0.f; M[11]=0.f;
            }   // invalid o>0: carry M forward

            unsigned long long* mp =
                (unsigned long long*)(out + MLV_OFF + (size_t)o * MLV_STRIDE) + 6 * g;
            atomicExch(&mp[0], pack2f(M[0], M[1]));
            atomicExch(&mp[1], pack2f(M[2], M[3]));
            atomicExch(&mp[2], pack2f(M[4], M[5]));
            atomicExch(&mp[3], pack2f(M[6], M[7]));
            atomicExch(&mp[4], pack2f(M[8], M[9]));
            atomicExch(&mp[5], pack2f(M[10], M[11]));
            __threadfence();
            atomicExch(&flags[g], (unsigned int)(o + 1));
        }
    }

    // ---- Stage 2: domain reduce + SVD ---------------------------------
    if (g < N_DOMAIN) {
        const int d = g;
        const float4* pv4 = (const float4*)pos;
        float a[15];
        #pragma unroll
        for (int k = 0; k < 15; k++) a[k] = 0.f;

        if (d >= N_TWIST / N_PER_DOM) {
            // high domain: P == Q, no torsion. 100 nodes = 75 float4s.
            int base = 75 * d;
            for (int c = 0; c < 25; c++) {
                float4 f0 = pv4[base + 3*c + 0];
                float4 f1 = pv4[base + 3*c + 1];
                float4 f2 = pv4[base + 3*c + 2];
                acc15(a, f0.x, f0.y, f0.z, f0.x, f0.y, f0.z);
                acc15(a, f0.w, f1.x, f1.y, f0.w, f1.x, f1.y);
                acc15(a, f1.z, f1.w, f2.x, f1.z, f1.w, f2.x);
                acc15(a, f2.y, f2.z, f2.w, f2.y, f2.z, f2.w);
            }
        } else {
            // low domain d covers nodes [100d,100d+100) = groups g0..g0+2
            int g0 = (100 * d) / K_TWIST;   // floor(2.5 d)
            float Mg[3][12];
            unsigned long long* M7 =
                (unsigned long long*)(out + MLV_OFF + (size_t)7 * MLV_STRIDE);
            #pragma unroll
            for (int j = 0; j < 3; j++) {
                spin_flag(&flags[g0 + j], 8u);
                read_M(M7 + 6 * (g0 + j), Mg[j]);
            }
            int n = d * N_PER_DOM, end = n + N_PER_DOM;
            while (n < end) {
                int gseg = n / K_TWIST;
                int segEnd = min(end, K_TWIST * (gseg + 1));
                const float* m = Mg[gseg - g0];
                float m0=m[0],m1=m[1],m2=m[2],m3=m[3],m4=m[4],m5=m[5];
                float m6=m[6],m7=m[7],m8=m[8],m9=m[9],m10=m[10],m11=m[11];
                int chunks = (segEnd - n) >> 2;
                int base = (3 * n) >> 2;
                for (int c = 0; c < chunks; c++) {
                    float4 f0 = pv4[base + 3*c + 0];
                    float4 f1 = pv4[base + 3*c + 1];
                    float4 f2 = pv4[base + 3*c + 2];
                    float q0, q1, q2, p0, p1, p2;
                    q0=f0.x; q1=f0.y; q2=f0.z;
                    p0=m0*q0+m1*q1+m2*q2+m9; p1=m3*q0+m4*q1+m5*q2+m10; p2=m6*q0+m7*q1+m8*q2+m11;
                    acc15(a, p0, p1, p2, q0, q1, q2);
                    q0=f0.w; q1=f1.x; q2=f1.y;
                    p0=m0*q0+m1*q1+m2*q2+m9; p1=m3*q0+m4*q1+m5*q2+m10; p2=m6*q0+m7*q1+m8*q2+m11;
                    acc15(a, p0, p1, p2, q0, q1, q2);
                    q0=f1.z; q1=f1.w; q2=f2.x;
                    p0=m0*q0+m1*q1+m2*q2+m9; p1=m3*q0+m4*q1+m5*q2+m10; p2=m6*q0+m7*q1+m8*q2+m11;
                    acc15(a, p0, p1, p2, q0, q1, q2);
                    q0=f2.y; q1=f2.z; q2=f2.w;
                    p0=m0*q0+m1*q1+m2*q2+m9; p1=m3*q0+m4*q1+m5*q2+m10; p2=m6*q0+m7*q1+m8*q2+m11;
                    acc15(a, p0, p1, p2, q0, q1, q2);
                }
                n = segEnd;
            }
        }
        kabsch_from_sums(a, rt + (size_t)d * 12);
    }
}

// ---------------------------------------------------------------------------
// apply_low_k: out[n] = W[d]*(Mf[g]*pos[n]) + t[d], n < N_TWIST. Reads
// M_lv[7] plain (atomic-written, post-boundary — R8-proven). Precedes high.
// ---------------------------------------------------------------------------
__global__ void apply_low_k(const float* __restrict__ pos,
                            const float* __restrict__ rt,
                            float* __restrict__ out)
{
    int n = blockIdx.x * 256 + threadIdx.x;
    if (n >= N_TWIST) return;
    const float* m = out + MLV_OFF + 7 * MLV_STRIDE + 12 * (n / K_TWIST);
    const float* w = rt + 12 * (n / N_PER_DOM);
    float q0 = pos[3*n+0], q1 = pos[3*n+1], q2 = pos[3*n+2];
    float p0 = m[0]*q0 + m[1]*q1 + m[2]*q2 + m[9];
    float p1 = m[3]*q0 + m[4]*q1 + m[5]*q2 + m[10];
    float p2 = m[6]*q0 + m[7]*q1 + m[8]*q2 + m[11];
    out[3*n+0] = w[0]*p0 + w[1]*p1 + w[2]*p2 + w[9];
    out[3*n+1] = w[3]*p0 + w[4]*p1 + w[5]*p2 + w[10];
    out[3*n+2] = w[6]*p0 + w[7]*p1 + w[8]*p2 + w[11];
}

// ---------------------------------------------------------------------------
// apply_high_k: out[n] = W[d]*pos[n] + t[d], n >= N_TWIST. Overwrites the
// M_lv scratch (all consumed). rt lives in ws.
// ---------------------------------------------------------------------------
__global__ void apply_high_k(const float* __restrict__ pos,
                             const float* __restrict__ rt,
                             float* __restrict__ out)
{
    int i = blockIdx.x * 256 + threadIdx.x;
    int n = N_TWIST + i;
    if (n >= N_NODE) return;
    const float* w = rt + 12 * (n / N_PER_DOM);
    float q0 = pos[3*n+0], q1 = pos[3*n+1], q2 = pos[3*n+2];
    out[3*n+0] = w[0]*q0 + w[1]*q1 + w[2]*q2 + w[9];
    out[3*n+1] = w[3]*q0 + w[4]*q1 + w[5]*q2 + w[10];
    out[3*n+2] = w[6]*q0 + w[7]*q1 + w[8]*q2 + w[11];
}

// ---------------------------------------------------------------------------
extern "C" void kernel_launch(void* const* d_in, const int* in_sizes, int n_in,
                              void* d_out, int out_size, void* d_ws, size_t ws_size,
                              hipStream_t stream)
{
    const float* pos        = (const float*)d_in[0];
    const float* info_level = (const float*)d_in[1];
    const int*   anno       = (const int*)  d_in[2];
    const float* eps        = (const float*)d_in[6];
    const float* uni        = (const float*)d_in[7];
    const int*   from_prior = (const int*)  d_in[8];
    float* out = (float*)d_out;
    float* rt  = (float*)d_ws;                                   // 480,000 B
    unsigned int* flags = (unsigned int*)((char*)d_ws + 480000); // +50,000 B

    // 1. fused gather + 8-level dataflow compose + domain reduce + SVD
    mega_k<<<(N_GROUP + 255)/256, 256, 0, stream>>>(
        pos, info_level, anno, eps, uni, from_prior, out, rt, flags);

    // 2. low nodes (reads M_lv[7] + rt), 3. high nodes (overwrites scratch)
    apply_low_k<<<(N_TWIST + 255)/256, 256, 0, stream>>>(pos, rt, out);
    apply_high_k<<<(N_NODE - N_TWIST + 255)/256, 256, 0, stream>>>(pos, rt, out);
}

// Round 10
// 192.487 us; speedup vs baseline: 1.1026x; 1.1026x over previous
//
#include <hip/hip_runtime.h>
#include <math.h>

#define N_NODE    1000000
#define N_BOND    100000
#define K_TWIST   40
#define MAX_ORDER 8
#define N_DOMAIN  10000
#define N_PER_DOM 100           // N_NODE / N_DOMAIN
#define N_GROUP   12500         // N_BOND / MAX_ORDER
#define N_TWIST   500000        // N_GROUP * K_TWIST  (nodes >= N_TWIST never twisted)
#define SIGMA_MAXF 3.14159265358979323846f

// Layout:
//   out-high floats: TA = [1.5M, 1.65M), TB = [1.65M, 1.8M) — M ping-pong.
//     Levels 0..6 only; level 6 (even) lands in TA = M6 table.
//     Level 7 is FOLDED into rsvd/apply_low (Mf = T7 ∘ M6, recomputed from
//     M6 + bond g*8+7 inputs — 2 L2-hot random M6 reads + 1 trig per group).
//   ws: rt only, 10000*12 floats = 480,000 B. HARD CEILING 600,000 B:
//     R2's post-timing divergence at 1.88 MB ws writes pins ws_size below
//     ~1.9 MB; 600 KB (R1) and 530 KB (R8/R9) are proven safe.
// Cost model (R4..R9): ~78 us fixed harness overhead + ~4 us per dispatch
// boundary. R4/R6/R8/R9 lessons: grid.sync (110 us), single-WG (no MLP),
// and atomic dataflow (8.5 us/level) ALL lose to plain whole-GPU dispatches.

#define TA_OFF  1500000
#define TB_OFF  1650000

// ---------------------------------------------------------------------------
// compose_k (R5-proven shape): one whole-GPU dispatch per level, one thread
// per group. Reads bond inputs directly + prev M table; writes cur M table.
// Level o even -> writes TA, odd -> writes TB  (prev is the other).
// ---------------------------------------------------------------------------
__global__ __launch_bounds__(256) void compose_k(
    const float* __restrict__ pos, const float* __restrict__ info_level,
    const int* __restrict__ anno, const float* __restrict__ eps,
    const float* __restrict__ uni, const int* __restrict__ from_prior_p,
    float* __restrict__ out, int o)
{
    int g = blockIdx.x * 256 + threadIdx.x;
    if (g >= N_GROUP) return;
    const float* Mp = out + ((o & 1) ? TA_OFF : TB_OFF);  // prev (o>0 only)
    float*       Mc = out + ((o & 1) ? TB_OFF : TA_OFF);  // cur
    int b = g * MAX_ORDER + o;
    float* mg = Mc + 12 * g;
    if (anno[3*b] != o) {                       // invalid: identity / carry
        if (o == 0) {
            mg[0]=1.f; mg[1]=0.f; mg[2]=0.f;
            mg[3]=0.f; mg[4]=1.f; mg[5]=0.f;
            mg[6]=0.f; mg[7]=0.f; mg[8]=1.f;
            mg[9]=0.f; mg[10]=0.f; mg[11]=0.f;
        } else {
            const float* mp = Mp + 12 * g;
            #pragma unroll
            for (int k = 0; k < 12; k++) mg[k] = mp[k];
        }
        return;
    }
    int u = anno[3*b + 1];
    int v = anno[3*b + 2];
    float pu0 = pos[3*u+0], pu1 = pos[3*u+1], pu2 = pos[3*u+2];
    float pv0 = pos[3*v+0], pv1 = pos[3*v+1], pv2 = pos[3*v+2];
    if (o > 0) {
        if (u < N_TWIST) {
            const float* m = Mp + 12 * (u / K_TWIST);
            float a0 = m[0]*pu0 + m[1]*pu1 + m[2]*pu2 + m[9];
            float a1 = m[3]*pu0 + m[4]*pu1 + m[5]*pu2 + m[10];
            float a2 = m[6]*pu0 + m[7]*pu1 + m[8]*pu2 + m[11];
            pu0 = a0; pu1 = a1; pu2 = a2;
        }
        if (v < N_TWIST) {
            const float* m = Mp + 12 * (v / K_TWIST);
            float a0 = m[0]*pv0 + m[1]*pv1 + m[2]*pv2 + m[9];
            float a1 = m[3]*pv0 + m[4]*pv1 + m[5]*pv2 + m[10];
            float a2 = m[6]*pv0 + m[7]*pv1 + m[8]*pv2 + m[11];
            pv0 = a0; pv1 = a1; pv2 = a2;
        }
    }
    float info = info_level[b];
    float ang  = eps[b] * (1.0f - info) * SIGMA_MAXF;
    if (from_prior_p[0] != 0 && info == 0.0f) ang = uni[b];
    float ax = pv0-pu0, ay = pv1-pu1, az = pv2-pu2;
    float inv = 1.0f / (sqrtf(ax*ax + ay*ay + az*az) + 1e-12f);
    ax *= inv; ay *= inv; az *= inv;
    float c = cosf(ang), s = sinf(ang), t = 1.0f - c;
    float R00 = c + t*ax*ax,     R01 = -s*az + t*ax*ay, R02 =  s*ay + t*ax*az;
    float R10 =  s*az + t*ay*ax, R11 = c + t*ay*ay,     R12 = -s*ax + t*ay*az;
    float R20 = -s*ay + t*az*ax, R21 =  s*ax + t*az*ay, R22 = c + t*az*az;
    if (o == 0) {
        mg[0]=R00; mg[1]=R01; mg[2]=R02;
        mg[3]=R10; mg[4]=R11; mg[5]=R12;
        mg[6]=R20; mg[7]=R21; mg[8]=R22;
        mg[9]  = pv0 - (R00*pv0 + R01*pv1 + R02*pv2);
        mg[10] = pv1 - (R10*pv0 + R11*pv1 + R12*pv2);
        mg[11] = pv2 - (R20*pv0 + R21*pv1 + R22*pv2);
    } else {
        const float* mp = Mp + 12 * g;
        mg[0] = R00*mp[0] + R01*mp[3] + R02*mp[6];
        mg[1] = R00*mp[1] + R01*mp[4] + R02*mp[7];
        mg[2] = R00*mp[2] + R01*mp[5] + R02*mp[8];
        mg[3] = R10*mp[0] + R11*mp[3] + R12*mp[6];
        mg[4] = R10*mp[1] + R11*mp[4] + R12*mp[7];
        mg[5] = R10*mp[2] + R11*mp[5] + R12*mp[8];
        mg[6] = R20*mp[0] + R21*mp[3] + R22*mp[6];
        mg[7] = R20*mp[1] + R21*mp[4] + R22*mp[7];
        mg[8] = R20*mp[2] + R21*mp[5] + R22*mp[8];
        float d0 = mp[9]-pv0, d1 = mp[10]-pv1, d2 = mp[11]-pv2;
        mg[9]  = R00*d0 + R01*d1 + R02*d2 + pv0;
        mg[10] = R10*d0 + R11*d1 + R12*d2 + pv1;
        mg[11] = R20*d0 + R21*d1 + R22*d2 + pv2;
    }
}

// ---------------------------------------------------------------------------
// final_M: the folded level 7.  Mf(g) = T7(g) ∘ M6(g), recomputed from the
// published M6 table + bond (g*8+7)'s inputs. Same arithmetic as compose_k.
// Used identically by rsvd_k and apply_low_k (shared function).
// ---------------------------------------------------------------------------
__device__ void final_M(const float* __restrict__ M6S,
                        const float* __restrict__ pos,
                        const float* __restrict__ info_level,
                        const int* __restrict__ anno,
                        const float* __restrict__ eps,
                        const float* __restrict__ uni,
                        int from_prior, int g, float Mf[12])
{
    const float* mp = M6S + 12 * g;
    int b = g * MAX_ORDER + 7;
    if (anno[3*b] != 7) {                        // invalid: carry M6
        #pragma unroll
        for (int k = 0; k < 12; k++) Mf[k] = mp[k];
        return;
    }
    int u = anno[3*b + 1];
    int v = anno[3*b + 2];
    float pu0 = pos[3*u+0], pu1 = pos[3*u+1], pu2 = pos[3*u+2];
    float pv0 = pos[3*v+0], pv1 = pos[3*v+1], pv2 = pos[3*v+2];
    if (u < N_TWIST) {
        const float* m = M6S + 12 * (u / K_TWIST);
        float a0 = m[0]*pu0 + m[1]*pu1 + m[2]*pu2 + m[9];
        float a1 = m[3]*pu0 + m[4]*pu1 + m[5]*pu2 + m[10];
        float a2 = m[6]*pu0 + m[7]*pu1 + m[8]*pu2 + m[11];
        pu0 = a0; pu1 = a1; pu2 = a2;
    }
    if (v < N_TWIST) {
        const float* m = M6S + 12 * (v / K_TWIST);
        float a0 = m[0]*pv0 + m[1]*pv1 + m[2]*pv2 + m[9];
        float a1 = m[3]*pv0 + m[4]*pv1 + m[5]*pv2 + m[10];
        float a2 = m[6]*pv0 + m[7]*pv1 + m[8]*pv2 + m[11];
        pv0 = a0; pv1 = a1; pv2 = a2;
    }
    float info = info_level[b];
    float ang  = eps[b] * (1.0f - info) * SIGMA_MAXF;
    if (from_prior != 0 && info == 0.0f) ang = uni[b];
    float ax = pv0-pu0, ay = pv1-pu1, az = pv2-pu2;
    float inv = 1.0f / (sqrtf(ax*ax + ay*ay + az*az) + 1e-12f);
    ax *= inv; ay *= inv; az *= inv;
    float c = cosf(ang), s = sinf(ang), t = 1.0f - c;
    float R00 = c + t*ax*ax,     R01 = -s*az + t*ax*ay, R02 =  s*ay + t*ax*az;
    float R10 =  s*az + t*ay*ax, R11 = c + t*ay*ay,     R12 = -s*ax + t*ay*az;
    float R20 = -s*ay + t*az*ax, R21 =  s*ax + t*az*ay, R22 = c + t*az*az;
    Mf[0] = R00*mp[0] + R01*mp[3] + R02*mp[6];
    Mf[1] = R00*mp[1] + R01*mp[4] + R02*mp[7];
    Mf[2] = R00*mp[2] + R01*mp[5] + R02*mp[8];
    Mf[3] = R10*mp[0] + R11*mp[3] + R12*mp[6];
    Mf[4] = R10*mp[1] + R11*mp[4] + R12*mp[7];
    Mf[5] = R10*mp[2] + R11*mp[5] + R12*mp[8];
    Mf[6] = R20*mp[0] + R21*mp[3] + R22*mp[6];
    Mf[7] = R20*mp[1] + R21*mp[4] + R22*mp[7];
    Mf[8] = R20*mp[2] + R21*mp[5] + R22*mp[8];
    float d0 = mp[9]-pv0, d1 = mp[10]-pv1, d2 = mp[11]-pv2;
    Mf[9]  = R00*d0 + R01*d1 + R02*d2 + pv0;
    Mf[10] = R10*d0 + R11*d1 + R12*d2 + pv1;
    Mf[11] = R20*d0 + R21*d1 + R22*d2 + pv2;
}

// ---------------------------------------------------------------------------
// Kabsch 3x3 SVD from 15 sums (double Jacobi on H^T H) — numerics identical
// to the R1..R9-verified version.
// ---------------------------------------------------------------------------
__device__ inline void cross3d(const double a[3], const double b[3], double r[3])
{
    r[0] = a[1]*b[2] - a[2]*b[1];
    r[1] = a[2]*b[0] - a[0]*b[2];
    r[2] = a[0]*b[1] - a[1]*b[0];
}

__device__ void kabsch_from_sums(const float* s, float* __restrict__ rt)
{
    const double inv_n = 1.0 / (double)N_PER_DOM;
    double sP[3] = { s[0], s[1], s[2] };
    double sQ[3] = { s[3], s[4], s[5] };
    double H[3][3];
    #pragma unroll
    for (int i = 0; i < 3; i++)
        #pragma unroll
        for (int j = 0; j < 3; j++)
            H[i][j] = (double)s[6 + 3*i + j] - sP[i]*sQ[j]*inv_n;
    double A[3][3];
    #pragma unroll
    for (int i = 0; i < 3; i++)
        #pragma unroll
        for (int j = 0; j < 3; j++)
            A[i][j] = H[0][i]*H[0][j] + H[1][i]*H[1][j] + H[2][i]*H[2][j];
    double V[3][3] = {{1,0,0},{0,1,0},{0,0,1}};
    for (int sweep = 0; sweep < 30; sweep++) {
        double off = A[0][1]*A[0][1] + A[0][2]*A[0][2] + A[1][2]*A[1][2];
        double n2  = A[0][0]*A[0][0] + A[1][1]*A[1][1] + A[2][2]*A[2][2];
        if (off <= 1e-28 * n2) break;
        for (int pp = 0; pp < 3; pp++) {
            int p = (pp == 2) ? 1 : 0;
            int q = (pp == 0) ? 1 : 2;
            double apq = A[p][q];
            if (apq == 0.0) continue;
            double tau = (A[q][q] - A[p][p]) / (2.0 * apq);
            double tj  = (tau >= 0.0 ? 1.0 : -1.0) / (fabs(tau) + sqrt(1.0 + tau*tau));
            double cj  = 1.0 / sqrt(1.0 + tj*tj);
            double sj  = tj * cj;
            int r = 3 - p - q;
            double app = A[p][p], aqq = A[q][q];
            A[p][p] = app - tj*apq;
            A[q][q] = aqq + tj*apq;
            A[p][q] = 0.0; A[q][p] = 0.0;
            double arp = A[r][p], arq = A[r][q];
            A[r][p] = cj*arp - sj*arq; A[p][r] = A[r][p];
            A[r][q] = sj*arp + cj*arq; A[q][r] = A[r][q];
            #pragma unroll
            for (int k = 0; k < 3; k++) {
                double vp = V[k][p], vq = V[k][q];
                V[k][p] = cj*vp - sj*vq;
                V[k][q] = sj*vp + cj*vq;
            }
        }
    }
    double wv[3] = { A[0][0], A[1][1], A[2][2] };
    int i0 = 0, i1 = 1, i2 = 2;
    if (wv[i0] < wv[i1]) { int t = i0; i0 = i1; i1 = t; }
    if (wv[i0] < wv[i2]) { int t = i0; i0 = i2; i2 = t; }
    if (wv[i1] < wv[i2]) { int t = i1; i1 = i2; i2 = t; }
    double v0[3] = { V[0][i0], V[1][i0], V[2][i0] };
    double v1[3] = { V[0][i1], V[1][i1], V[2][i1] };
    double v2[3] = { V[0][i2], V[1][i2], V[2][i2] };
    double s0 = sqrt(fmax(wv[i0], 0.0));
    double Rg[3][3];
    if (s0 < 1e-200) {
        Rg[0][0]=1; Rg[0][1]=0; Rg[0][2]=0;
        Rg[1][0]=0; Rg[1][1]=1; Rg[1][2]=0;
        Rg[2][0]=0; Rg[2][1]=0; Rg[2][2]=1;
    } else {
        double u0[3], u1[3], u2[3];
        #pragma unroll
        for (int i = 0; i < 3; i++)
            u0[i] = H[i][0]*v0[0] + H[i][1]*v0[1] + H[i][2]*v0[2];
        double n0 = sqrt(u0[0]*u0[0] + u0[1]*u0[1] + u0[2]*u0[2]);
        if (n0 > 0.0) { u0[0]/=n0; u0[1]/=n0; u0[2]/=n0; }
        else { u0[0]=1; u0[1]=0; u0[2]=0; }
        #pragma unroll
        for (int i = 0; i < 3; i++)
            u1[i] = H[i][0]*v1[0] + H[i][1]*v1[1] + H[i][2]*v1[2];
        double dp = u0[0]*u1[0] + u0[1]*u1[1] + u0[2]*u1[2];
        u1[0] -= dp*u0[0]; u1[1] -= dp*u0[1]; u1[2] -= dp*u0[2];
        double n1 = sqrt(u1[0]*u1[0] + u1[1]*u1[1] + u1[2]*u1[2]);
        if (n1 > 1e-12 * n0) { u1[0]/=n1; u1[1]/=n1; u1[2]/=n1; }
        else {
            double tv[3] = { (fabs(u0[0]) < 0.9) ? 1.0 : 0.0,
                             (fabs(u0[0]) < 0.9) ? 0.0 : 1.0, 0.0 };
            cross3d(u0, tv, u1);
            double nn = sqrt(u1[0]*u1[0] + u1[1]*u1[1] + u1[2]*u1[2]);
            u1[0]/=nn; u1[1]/=nn; u1[2]/=nn;
        }
        cross3d(u0, u1, u2);                    // det(U) = +1
        double c12[3]; cross3d(v1, v2, c12);
        double detV = v0[0]*c12[0] + v0[1]*c12[1] + v0[2]*c12[2];
        double dsg = (detV >= 0.0) ? 1.0 : -1.0;
        #pragma unroll
        for (int r = 0; r < 3; r++)
            #pragma unroll
            for (int c = 0; c < 3; c++)
                Rg[r][c] = v0[r]*u0[c] + v1[r]*u1[c] + dsg*v2[r]*u2[c];
    }
    double cP[3] = { sP[0]*inv_n, sP[1]*inv_n, sP[2]*inv_n };
    double cQ[3] = { sQ[0]*inv_n, sQ[1]*inv_n, sQ[2]*inv_n };
    #pragma unroll
    for (int i = 0; i < 3; i++) {
        rt[3*i+0] = (float)Rg[i][0];
        rt[3*i+1] = (float)Rg[i][1];
        rt[3*i+2] = (float)Rg[i][2];
        rt[9+i] = (float)(cQ[i] - (Rg[i][0]*cP[0] + Rg[i][1]*cP[1] + Rg[i][2]*cP[2]));
    }
}

__device__ inline void acc15(float a[15], float p0, float p1, float p2,
                             float q0, float q1, float q2)
{
    a[0]+=p0;    a[1]+=p1;    a[2]+=p2;
    a[3]+=q0;    a[4]+=q1;    a[5]+=q2;
    a[6]+=p0*q0; a[7]+=p0*q1; a[8]+=p0*q2;
    a[9]+=p1*q0; a[10]+=p1*q1;a[11]+=p1*q2;
    a[12]+=p2*q0;a[13]+=p2*q1;a[14]+=p2*q2;
}

// ---------------------------------------------------------------------------
// rsvd_k: THREAD per domain (64-thread blocks -> 157 blocks spread over
// 157 CUs). Low domains build Mf for their 3 covering groups via final_M
// (folded level 7), reduce 100 contiguous nodes (float4), then double-Jacobi
// SVD -> rt (ws). R6/R7-proven structure + the fold.
// ---------------------------------------------------------------------------
__global__ __launch_bounds__(64) void rsvd_k(
    const float* __restrict__ pos, const float* __restrict__ info_level,
    const int* __restrict__ anno, const float* __restrict__ eps,
    const float* __restrict__ uni, const int* __restrict__ from_prior_p,
    const float* __restrict__ out, float* __restrict__ rt)
{
    int d = blockIdx.x * 64 + threadIdx.x;
    if (d >= N_DOMAIN) return;
    const float4* pv4 = (const float4*)pos;
    float a[15];
    #pragma unroll
    for (int k = 0; k < 15; k++) a[k] = 0.f;

    if (d >= N_TWIST / N_PER_DOM) {
        // high domain: P == Q. 100 nodes = 75 float4s.
        int base = 75 * d;
        for (int c = 0; c < 25; c++) {
            float4 f0 = pv4[base + 3*c + 0];
            float4 f1 = pv4[base + 3*c + 1];
            float4 f2 = pv4[base + 3*c + 2];
            acc15(a, f0.x, f0.y, f0.z, f0.x, f0.y, f0.z);
            acc15(a, f0.w, f1.x, f1.y, f0.w, f1.x, f1.y);
            acc15(a, f1.z, f1.w, f2.x, f1.z, f1.w, f2.x);
            acc15(a, f2.y, f2.z, f2.w, f2.y, f2.z, f2.w);
        }
    } else {
        const float* M6S = out + TA_OFF;
        int g0 = (100 * d) / K_TWIST;           // 3 covering groups g0..g0+2
        float Mg[3][12];
        int from_prior = from_prior_p[0];
        #pragma unroll
        for (int j = 0; j < 3; j++)
            final_M(M6S, pos, info_level, anno, eps, uni, from_prior,
                    g0 + j, Mg[j]);
        int n = d * N_PER_DOM, end = n + N_PER_DOM;
        while (n < end) {
            int gseg = n / K_TWIST;
            int segEnd = min(end, K_TWIST * (gseg + 1));
            const float* m = Mg[gseg - g0];
            float m0=m[0],m1=m[1],m2=m[2],m3=m[3],m4=m[4],m5=m[5];
            float m6=m[6],m7=m[7],m8=m[8],m9=m[9],m10=m[10],m11=m[11];
            int chunks = (segEnd - n) >> 2;
            int base = (3 * n) >> 2;
            for (int c = 0; c < chunks; c++) {
                float4 f0 = pv4[base + 3*c + 0];
                float4 f1 = pv4[base + 3*c + 1];
                float4 f2 = pv4[base + 3*c + 2];
                float q0, q1, q2, p0, p1, p2;
                q0=f0.x; q1=f0.y; q2=f0.z;
                p0=m0*q0+m1*q1+m2*q2+m9; p1=m3*q0+m4*q1+m5*q2+m10; p2=m6*q0+m7*q1+m8*q2+m11;
                acc15(a, p0, p1, p2, q0, q1, q2);
                q0=f0.w; q1=f1.x; q2=f1.y;
                p0=m0*q0+m1*q1+m2*q2+m9; p1=m3*q0+m4*q1+m5*q2+m10; p2=m6*q0+m7*q1+m8*q2+m11;
                acc15(a, p0, p1, p2, q0, q1, q2);
                q0=f1.z; q1=f1.w; q2=f2.x;
                p0=m0*q0+m1*q1+m2*q2+m9; p1=m3*q0+m4*q1+m5*q2+m10; p2=m6*q0+m7*q1+m8*q2+m11;
                acc15(a, p0, p1, p2, q0, q1, q2);
                q0=f2.y; q1=f2.z; q2=f2.w;
                p0=m0*q0+m1*q1+m2*q2+m9; p1=m3*q0+m4*q1+m5*q2+m10; p2=m6*q0+m7*q1+m8*q2+m11;
                acc15(a, p0, p1, p2, q0, q1, q2);
            }
            n = segEnd;
        }
    }
    kabsch_from_sums(a, rt + (size_t)d * 12);
}

// ---------------------------------------------------------------------------
// apply_low_k: out[n] = W[d]*(Mf(g)*pos[n]) + t[d], n < N_TWIST. Mf via
// final_M (folded level 7; 40 threads/group read identical M6/bond addresses
// -> broadcast). Reads TA (out-high) — must precede apply_high_k.
// ---------------------------------------------------------------------------
__global__ __launch_bounds__(256) void apply_low_k(
    const float* __restrict__ pos, const float* __restrict__ info_level,
    const int* __restrict__ anno, const float* __restrict__ eps,
    const float* __restrict__ uni, const int* __restrict__ from_prior_p,
    const float* __restrict__ rt, float* __restrict__ out)
{
    int n = blockIdx.x * 256 + threadIdx.x;
    if (n >= N_TWIST) return;
    float m[12];
    final_M(out + TA_OFF, pos, info_level, anno, eps, uni, from_prior_p[0],
            n / K_TWIST, m);
    const float* w = rt + 12 * (n / N_PER_DOM);
    float q0 = pos[3*n+0], q1 = pos[3*n+1], q2 = pos[3*n+2];
    float p0 = m[0]*q0 + m[1]*q1 + m[2]*q2 + m[9];
    float p1 = m[3]*q0 + m[4]*q1 + m[5]*q2 + m[10];
    float p2 = m[6]*q0 + m[7]*q1 + m[8]*q2 + m[11];
    out[3*n+0] = w[0]*p0 + w[1]*p1 + w[2]*p2 + w[9];
    out[3*n+1] = w[3]*p0 + w[4]*p1 + w[5]*p2 + w[10];
    out[3*n+2] = w[6]*p0 + w[7]*p1 + w[8]*p2 + w[11];
}

// ---------------------------------------------------------------------------
// apply_high_k: out[n] = W[d]*pos[n] + t[d], n >= N_TWIST. Overwrites the
// TA/TB scratch (all consumed). rt lives in ws.
// ---------------------------------------------------------------------------
__global__ __launch_bounds__(256) void apply_high_k(
    const float* __restrict__ pos, const float* __restrict__ rt,
    float* __restrict__ out)
{
    int i = blockIdx.x * 256 + threadIdx.x;
    int n = N_TWIST + i;
    if (n >= N_NODE) return;
    const float* w = rt + 12 * (n / N_PER_DOM);
    float q0 = pos[3*n+0], q1 = pos[3*n+1], q2 = pos[3*n+2];
    out[3*n+0] = w[0]*q0 + w[1]*q1 + w[2]*q2 + w[9];
    out[3*n+1] = w[3]*q0 + w[4]*q1 + w[5]*q2 + w[10];
    out[3*n+2] = w[6]*q0 + w[7]*q1 + w[8]*q2 + w[11];
}

// ---------------------------------------------------------------------------
extern "C" void kernel_launch(void* const* d_in, const int* in_sizes, int n_in,
                              void* d_out, int out_size, void* d_ws, size_t ws_size,
                              hipStream_t stream)
{
    const float* pos        = (const float*)d_in[0];
    const float* info_level = (const float*)d_in[1];
    const int*   anno       = (const int*)  d_in[2];
    const float* eps        = (const float*)d_in[6];
    const float* uni        = (const float*)d_in[7];
    const int*   from_prior = (const int*)  d_in[8];
    float* out = (float*)d_out;
    float* rt  = (float*)d_ws;                       // 480,000 B (proven safe)

    // 1-7. compose levels 0..6 (level 6 lands in TA = M6 table)
    for (int o = 0; o < 7; o++)
        compose_k<<<(N_GROUP + 255)/256, 256, 0, stream>>>(
            pos, info_level, anno, eps, uni, from_prior, out, o);

    // 8. per-domain reduce + SVD (folded level 7), thread per domain
    rsvd_k<<<(N_DOMAIN + 63)/64, 64, 0, stream>>>(
        pos, info_level, anno, eps, uni, from_prior, out, rt);

    // 9. low nodes (folded level 7; reads TA), 10. high nodes (overwrites TA/TB)
    apply_low_k<<<(N_TWIST + 255)/256, 256, 0, stream>>>(
        pos, info_level, anno, eps, uni, from_prior, rt, out);
    apply_high_k<<<(N_NODE - N_TWIST + 255)/256, 256, 0, stream>>>(pos, rt, out);
}